// Round 11
// baseline (103.654 us; speedup 1.0000x reference)
//
#include <hip/hip_runtime.h>

#if __has_builtin(__builtin_amdgcn_exp2f)
#define EXP2F(x) __builtin_amdgcn_exp2f(x)
#else
#define EXP2F(x) exp2f(x)
#endif

typedef float v2f __attribute__((ext_vector_type(2)));
typedef _Float16 h2v __attribute__((ext_vector_type(2)));   // 4B
typedef _Float16 h4v __attribute__((ext_vector_type(4)));   // 8B

constexpr int B = 8, H = 512, W = 512;
constexpr int PLANE = H * W;              // 262144
constexpr int BSTRIDE = 2 * PLANE;
constexpr int NPIX = B * PLANE;           // 2097152
constexpr int PPITCH = 520;               // padded row pitch (4 left, 4 right)
constexpr int PXOFF  = 4;
constexpr int PPLANE = H * PPITCH;        // 266240 halves per (b,ch) plane
constexpr int PBUF   = 16 * PPLANE;       // 4,259,840 halves per padded tensor (8.5MB)
constexpr float LOG2E = 1.4426950408889634f;

__device__ __forceinline__ float reluf(float v) { return v > 0.f ? v : 0.f; }
__device__ __forceinline__ float frcp(float v) { return __builtin_amdgcn_rcpf(v); }
__device__ __forceinline__ v2f vfma(v2f a, v2f b, v2f c) { return __builtin_elementwise_fma(a, b, c); }
__device__ __forceinline__ v2f vmax2(v2f a, v2f b) { return __builtin_elementwise_max(a, b); }
__device__ __forceinline__ v2f bc(float x) { v2f r; r.x = x; r.y = x; return r; }

// XCD-aware bijective work swizzle (8 XCDs, nwg % 8 == 0)
__device__ __forceinline__ unsigned swz8(unsigned bid, unsigned nwg)
{
    return (bid & 7u) * (nwg >> 3) + (bid >> 3);
}

struct AttnW {
    v2f wq0, wq1, bq;
    v2f wk0, wk1;
    v2f biasK[3];              // ((bk0+rh[r])*L, bk1*L)
    float rwL[3];              // rw[d]*L (ch1 additive)
    v2f wv0, wv1, bv;
};

__device__ __forceinline__ AttnW load_w(
    const float* wq, const float* bq, const float* wk, const float* bk,
    const float* wv, const float* bv, const float* rh, const float* rw, int i)
{
    AttnW P;
    P.wq0.x = wq[4*i];   P.wq0.y = wq[4*i+2];
    P.wq1.x = wq[4*i+1]; P.wq1.y = wq[4*i+3];
    P.bq.x  = bq[2*i];   P.bq.y  = bq[2*i+1];
    P.wk0.x = wk[4*i]   * LOG2E; P.wk0.y = wk[4*i+2] * LOG2E;
    P.wk1.x = wk[4*i+1] * LOG2E; P.wk1.y = wk[4*i+3] * LOG2E;
    float bk1L = bk[2*i+1] * LOG2E;
#pragma unroll
    for (int r = 0; r < 3; ++r) {
        P.biasK[r].x = (bk[2*i] + rh[3*i+r]) * LOG2E;
        P.biasK[r].y = bk1L;
    }
#pragma unroll
    for (int d = 0; d < 3; ++d) P.rwL[d] = rw[3*i+d] * LOG2E;
    P.wv0.x = wv[4*i];   P.wv0.y = wv[4*i+2];
    P.wv1.x = wv[4*i+1]; P.wv1.y = wv[4*i+3];
    P.bv.x  = bv[2*i];   P.bv.y  = bv[2*i+1];
    return P;
}

__device__ __forceinline__ void attn_strip(
    const v2f (&t)[3][6], const AttnW& P, v2f (&o)[4])
{
    v2f kk[3][6], vv[3][6];
#pragma unroll
    for (int r = 0; r < 3; ++r)
#pragma unroll
        for (int c = 0; c < 6; ++c) {
            v2f u0 = bc(t[r][c].x), u1 = bc(t[r][c].y);
            kk[r][c] = vfma(P.wk0, u0, vfma(P.wk1, u1, P.biasK[r]));
            vv[r][c] = vfma(P.wv0, u0, vfma(P.wv1, u1, P.bv));
        }
#pragma unroll
    for (int px = 0; px < 4; ++px) {
        v2f q = vfma(P.wq0, bc(t[1][px+1].x), vfma(P.wq1, bc(t[1][px+1].y), P.bq));
        v2f addv[3];
#pragma unroll
        for (int d = 0; d < 3; ++d) { addv[d].x = 0.f; addv[d].y = q.y * P.rwL[d]; }
        v2f s[9];
#pragma unroll
        for (int r = 0; r < 3; ++r)
#pragma unroll
            for (int d = 0; d < 3; ++d)
                s[r*3+d] = vfma(q, kk[r][px+d], addv[d]);
        v2f m = vmax2(vmax2(vmax2(vmax2(s[0], s[1]), vmax2(s[2], s[3])),
                            vmax2(vmax2(s[4], s[5]), vmax2(s[6], s[7]))), s[8]);
        v2f sum = bc(0.f), acc = bc(0.f);
#pragma unroll
        for (int r = 0; r < 3; ++r)
#pragma unroll
            for (int d = 0; d < 3; ++d) {
                v2f dd = s[r*3+d] - m;
                v2f e; e.x = EXP2F(dd.x); e.y = EXP2F(dd.y);
                sum += e;
                acc = vfma(e, vv[r][px+d], acc);
            }
        v2f rs; rs.x = frcp(sum.x); rs.y = frcp(sum.y);
        o[px] = acc * rs;
    }
}

// ---- fp16 padded-tensor helpers ----

// store 4-px strip (both channels), optional relu, + zero x-pads at row edges
template<bool RELU>
__device__ __forceinline__ void store_padded_h(
    _Float16* outp, int b2, int y, int x0, const v2f (&o)[4])
{
    int ob = b2 * PPLANE + y * PPITCH + x0 + PXOFF;   // multiple of 4 -> 8B aligned
    h4v h0, h1;
#pragma unroll
    for (int j = 0; j < 4; ++j) {
        float vx = RELU ? reluf(o[j].x) : o[j].x;
        float vy = RELU ? reluf(o[j].y) : o[j].y;
        h0[j] = (_Float16)vx;
        h1[j] = (_Float16)vy;
    }
    *reinterpret_cast<h4v*>(outp + ob)          = h0;
    *reinterpret_cast<h4v*>(outp + ob + PPLANE) = h1;
    if (x0 == 0 || x0 == W - 4) {
        h4v z; z.x = z.y = z.z = z.w = (_Float16)0.f;
        int pb = b2 * PPLANE + y * PPITCH + (x0 == 0 ? 0 : PXOFF + W);
        *reinterpret_cast<h4v*>(outp + pb)          = z;
        *reinterpret_cast<h4v*>(outp + pb + PPLANE) = z;
    }
}

// load 3x6 neighborhood from padded fp16 tensor (x-pads zero, y wave-uniform).
// 3 loads per row-ch: h4v centers + 2 scalar edges.
template<bool DO_RELU>
__device__ __forceinline__ void load_t_padded_h(
    unsigned s, const _Float16* __restrict__ xp, v2f (&t)[3][6])
{
    int x0 = (s & 127) * 4;
    int y  = (s >> 7) & 511;
    int b  = s >> 16;

    const _Float16* xb0 = xp + (b * 2) * PPLANE + x0 + PXOFF;
#pragma unroll
    for (int r = 0; r < 3; ++r) {
        int gy = y - 1 + r;
        bool ok = (unsigned)gy < (unsigned)H;   // wave-uniform
        int gyc = ok ? gy : y;
        const _Float16* p0 = xb0 + gyc * PPITCH;
        const _Float16* p1 = p0 + PPLANE;
        h4v m0 = *reinterpret_cast<const h4v*>(p0);
        h4v m1 = *reinterpret_cast<const h4v*>(p1);
        float l0 = (float)p0[-1], r0e = (float)p0[4];
        float l1 = (float)p1[-1], r1e = (float)p1[4];
        if (ok) {
            float u0[6] = { l0, (float)m0.x, (float)m0.y, (float)m0.z, (float)m0.w, r0e };
            float u1[6] = { l1, (float)m1.x, (float)m1.y, (float)m1.z, (float)m1.w, r1e };
#pragma unroll
            for (int c = 0; c < 6; ++c) {
                t[r][c].x = DO_RELU ? reluf(u0[c]) : u0[c];
                t[r][c].y = DO_RELU ? reluf(u1[c]) : u1[c];
            }
        } else {
#pragma unroll
            for (int c = 0; c < 6; ++c) { t[r][c].x = 0.f; t[r][c].y = 0.f; }
        }
    }
}

// load relu'd 3x6 neighborhood from UNPADDED f32 tensor (bounds-checked),
// also returning the RAW center float4s (both channels) for residual use.
__device__ __forceinline__ void load_t_unpadded(
    unsigned s, const float* __restrict__ x, v2f (&t)[3][6],
    float4& c0raw, float4& c1raw)
{
    int x0 = (s & 127) * 4;
    int y  = (s >> 7) & 511;
    int b  = s >> 16;

    const float* xb = x + b * BSTRIDE;
    bool rowv[3] = { y > 0, true, y < H - 1 };
    int  yr[3]   = { y > 0 ? y - 1 : 0, y, y < H - 1 ? y + 1 : H - 1 };
    bool lv   = x0 > 0;
    bool rvld = x0 < W - 4;
    int  xl = lv ? x0 - 1 : 0;
    int  xr = rvld ? x0 + 4 : W - 1;

#pragma unroll
    for (int r = 0; r < 3; ++r) {
        const float* p0 = xb + yr[r] * W;
        const float* p1 = p0 + PLANE;
        float4 a0 = *reinterpret_cast<const float4*>(p0 + x0);
        float4 a1 = *reinterpret_cast<const float4*>(p1 + x0);
        if (r == 1) { c0raw = a0; c1raw = a1; }
        float u0[6] = { p0[xl], a0.x, a0.y, a0.z, a0.w, p0[xr] };
        float u1[6] = { p1[xl], a1.x, a1.y, a1.z, a1.w, p1[xr] };
        bool rv_ = rowv[r];
#pragma unroll
        for (int c = 0; c < 6; ++c) {
            bool ok = rv_ && (c > 0 || lv) && (c < 5 || rvld);
            t[r][c].x = ok ? reluf(u0[c]) : 0.f;
            t[r][c].y = ok ? reluf(u1[c]) : 0.f;
        }
    }
}

// ---------------- kernels ----------------

// K1: t1 = relu(attn0(relu(in1))) -> A ; t3 = relu(attn2(relu(in2))) -> B ;
//     rsum = fp16(in1 + in2) -> R (unpadded fp16)
__global__ __launch_bounds__(256) void attn_in_kernel(
    const float* __restrict__ in1, const float* __restrict__ in2,
    _Float16* outA, _Float16* outB, _Float16* rsum,
    const float* __restrict__ wq, const float* __restrict__ bq,
    const float* __restrict__ wk, const float* __restrict__ bk,
    const float* __restrict__ wv, const float* __restrict__ bv,
    const float* __restrict__ rh, const float* __restrict__ rw)
{
    unsigned s = swz8(blockIdx.x, 2048) * 256u + threadIdx.x;
    int x0 = (s & 127) * 4;
    int y  = (s >> 7) & 511;
    int b  = s >> 16;

    v2f t[3][6];
    v2f o[4];
    float4 c0a, c1a, c0b, c1b;

    {
        AttnW P0 = load_w(wq, bq, wk, bk, wv, bv, rh, rw, 0);
        load_t_unpadded(s, in1, t, c0a, c1a);
        attn_strip(t, P0, o);
        store_padded_h<true>(outA, b * 2, y, x0, o);
    }
    {
        AttnW P2 = load_w(wq, bq, wk, bk, wv, bv, rh, rw, 2);
        load_t_unpadded(s, in2, t, c0b, c1b);
        attn_strip(t, P2, o);
        store_padded_h<true>(outB, b * 2, y, x0, o);
    }

    int base0 = b * BSTRIDE + y * W + x0;
    h4v r0h, r1h;
    r0h.x = (_Float16)(c0a.x + c0b.x); r0h.y = (_Float16)(c0a.y + c0b.y);
    r0h.z = (_Float16)(c0a.z + c0b.z); r0h.w = (_Float16)(c0a.w + c0b.w);
    r1h.x = (_Float16)(c1a.x + c1b.x); r1h.y = (_Float16)(c1a.y + c1b.y);
    r1h.z = (_Float16)(c1a.z + c1b.z); r1h.w = (_Float16)(c1a.w + c1b.w);
    *reinterpret_cast<h4v*>(rsum + base0)         = r0h;
    *reinterpret_cast<h4v*>(rsum + base0 + PLANE) = r1h;
}

// K23 (fused): s = attn1(t1) + attn3(t3) + rsum -> C (fp16 padded, raw)
__global__ __launch_bounds__(256) void attn_fused23_kernel(
    const _Float16* __restrict__ A, const _Float16* __restrict__ Bb,
    const _Float16* __restrict__ rsum,
    _Float16* __restrict__ C,
    const float* __restrict__ wq, const float* __restrict__ bq,
    const float* __restrict__ wk, const float* __restrict__ bk,
    const float* __restrict__ wv, const float* __restrict__ bv,
    const float* __restrict__ rh, const float* __restrict__ rw)
{
    unsigned s = swz8(blockIdx.x, 2048) * 256u + threadIdx.x;
    int x0 = (s & 127) * 4;
    int y  = (s >> 7) & 511;
    int b  = s >> 16;

    v2f t[3][6];
    v2f o1[4], o2[4];

    {
        AttnW P1 = load_w(wq, bq, wk, bk, wv, bv, rh, rw, 1);
        load_t_padded_h<false>(s, A, t);    // t1 stored pre-relu'd
        attn_strip(t, P1, o1);
    }
    {
        AttnW P3 = load_w(wq, bq, wk, bk, wv, bv, rh, rw, 3);
        load_t_padded_h<false>(s, Bb, t);   // t3 stored pre-relu'd
        attn_strip(t, P3, o2);
    }

    int base0 = b * BSTRIDE + y * W + x0;
    h4v r0 = *reinterpret_cast<const h4v*>(rsum + base0);
    h4v r1 = *reinterpret_cast<const h4v*>(rsum + base0 + PLANE);
#pragma unroll
    for (int j = 0; j < 4; ++j) {
        o2[j].x += o1[j].x + (float)r0[j];
        o2[j].y += o1[j].y + (float)r1[j];
    }

    store_padded_h<false>(C, b * 2, y, x0, o2);   // s raw (K5 residual needs it)
}

// K4: t5 = relu(attn4(relu(s))) -> B (fp16 padded)
__global__ __launch_bounds__(256) void attn4_kernel(
    const _Float16* __restrict__ C, _Float16* __restrict__ Bb,
    const float* __restrict__ wq, const float* __restrict__ bq,
    const float* __restrict__ wk, const float* __restrict__ bk,
    const float* __restrict__ wv, const float* __restrict__ bv,
    const float* __restrict__ rh, const float* __restrict__ rw)
{
    unsigned s = swz8(blockIdx.x, 2048) * 256u + threadIdx.x;
    AttnW P = load_w(wq, bq, wk, bk, wv, bv, rh, rw, 4);
    v2f t[3][6];
    load_t_padded_h<true>(s, C, t);        // s is raw -> relu on load
    v2f o[4];
    attn_strip(t, P, o);
    store_padded_h<true>(Bb, (s >> 16) * 2, (s >> 7) & 511, (s & 127) * 4, o);
}

// K5: u = attn5(t5) + s -> C in-place (own-pixel read+write; pads untouched)
__global__ __launch_bounds__(256) void attn5_kernel(
    const _Float16* __restrict__ Bb, _Float16* __restrict__ C,
    const float* __restrict__ wq, const float* __restrict__ bq,
    const float* __restrict__ wk, const float* __restrict__ bk,
    const float* __restrict__ wv, const float* __restrict__ bv,
    const float* __restrict__ rh, const float* __restrict__ rw)
{
    unsigned s = swz8(blockIdx.x, 2048) * 256u + threadIdx.x;
    AttnW P = load_w(wq, bq, wk, bk, wv, bv, rh, rw, 5);
    v2f t[3][6];
    load_t_padded_h<false>(s, Bb, t);      // t5 stored pre-relu'd
    v2f o[4];
    attn_strip(t, P, o);

    int x0 = (s & 127) * 4;
    int y  = (s >> 7) & 511;
    int b  = s >> 16;
    int ob = (b * 2) * PPLANE + y * PPITCH + x0 + PXOFF;
    h4v r0 = *reinterpret_cast<const h4v*>(C + ob);
    h4v r1 = *reinterpret_cast<const h4v*>(C + ob + PPLANE);
    h4v h0, h1;
#pragma unroll
    for (int j = 0; j < 4; ++j) {
        h0[j] = (_Float16)(o[j].x + (float)r0[j]);
        h1[j] = (_Float16)(o[j].y + (float)r1[j]);
    }
    *reinterpret_cast<h4v*>(C + ob)          = h0;
    *reinterpret_cast<h4v*>(C + ob + PPLANE) = h1;
}

// K6: o = sigmoid(conv3x3(reflect_pad(u))) ; u fp16 padded -> f32 out[0:2M]
__global__ __launch_bounds__(256) void conv_sig4_kernel(
    const _Float16* __restrict__ u,
    const float* __restrict__ cw, const float* __restrict__ cb,
    float* __restrict__ o)
{
    unsigned s = swz8(blockIdx.x, 2048) * 256u + threadIdx.x;
    int x0 = (s & 127) * 4;
    int y  = (s >> 7) & 511;
    int b  = s >> 16;

    float w[18];
#pragma unroll
    for (int i = 0; i < 18; ++i) w[i] = cw[i];

    int yy[3];
#pragma unroll
    for (int i = 0; i < 3; ++i) {
        int t = y + i - 1;
        if (t < 0) t = -t;
        if (t > H - 1) t = 2 * (H - 1) - t;
        yy[i] = t;
    }
    int xl = x0 - 1; if (xl < 0) xl = 1;
    int xr = x0 + 4; if (xr > W - 1) xr = 2 * (W - 1) - xr;

    float acc[4] = { cb[0], cb[0], cb[0], cb[0] };
#pragma unroll
    for (int c = 0; c < 2; ++c) {
        const _Float16* up = u + (b * 2 + c) * PPLANE + PXOFF;
#pragma unroll
        for (int i = 0; i < 3; ++i) {
            const _Float16* row = up + yy[i] * PPITCH;
            h4v m0 = *reinterpret_cast<const h4v*>(row + x0);
            float t6[6] = { (float)row[xl], (float)m0.x, (float)m0.y,
                            (float)m0.z, (float)m0.w, (float)row[xr] };
#pragma unroll
            for (int j = 0; j < 3; ++j) {
                float wc = w[c * 9 + i * 3 + j];
#pragma unroll
                for (int px = 0; px < 4; ++px)
                    acc[px] = fmaf(t6[px + j], wc, acc[px]);
            }
        }
    }
    float4 ov;
    ov.x = frcp(1.f + EXP2F(-acc[0] * LOG2E));
    ov.y = frcp(1.f + EXP2F(-acc[1] * LOG2E));
    ov.z = frcp(1.f + EXP2F(-acc[2] * LOG2E));
    ov.w = frcp(1.f + EXP2F(-acc[3] * LOG2E));
    *reinterpret_cast<float4*>(o + b * PLANE + y * W + x0) = ov;
}

// K7: 2x bilinear upsample (linspace(0,511,1024) grid); o is f32
__global__ __launch_bounds__(256) void upsample4_kernel(
    const float* __restrict__ o, float* __restrict__ up)
{
    unsigned p = swz8(blockIdx.x, 8192) * 256u + threadIdx.x;
    int b  = p >> 18;
    int y  = (p >> 8) & 1023;
    int x0 = (p & 255) * 4;

    const float scale = 511.0f / 1023.0f;
    float fy = y * scale;
    int y0 = (int)fy;
    float wy = fy - y0;
    int y1 = min(y0 + 1, H - 1);

    const float* ob = o + b * PLANE;
    const float* row0 = ob + y0 * W;
    const float* row1 = ob + y1 * W;

    float4 ov;
    float* ovp = &ov.x;
#pragma unroll
    for (int j = 0; j < 4; ++j) {
        float fx = (x0 + j) * scale;
        int xi = (int)fx;
        float wx = fx - xi;
        int xi1 = min(xi + 1, W - 1);
        float v00 = row0[xi], v01 = row0[xi1];
        float v10 = row1[xi], v11 = row1[xi1];
        float top = fmaf(v01 - v00, wx, v00);
        float bot = fmaf(v11 - v10, wx, v10);
        ovp[j] = fmaf(bot - top, wy, top);
    }
    *reinterpret_cast<float4*>(up + ((long)b << 20) + y * 1024 + x0) = ov;
}

extern "C" void kernel_launch(void* const* d_in, const int* in_sizes, int n_in,
                              void* d_out, int out_size, void* d_ws, size_t ws_size,
                              hipStream_t stream) {
    const float* in1 = (const float*)d_in[0];
    const float* in2 = (const float*)d_in[1];
    const float* wq  = (const float*)d_in[2];
    const float* bq  = (const float*)d_in[3];
    const float* wk  = (const float*)d_in[4];
    const float* bk  = (const float*)d_in[5];
    const float* wv  = (const float*)d_in[6];
    const float* bv  = (const float*)d_in[7];
    const float* rh  = (const float*)d_in[8];
    const float* rw  = (const float*)d_in[9];
    const float* cw  = (const float*)d_in[10];
    const float* cb  = (const float*)d_in[11];

    float* out = (float*)d_out;
    // fp16 buffers in d_out (total 41.94MB):
    //   A    = t1           bytes [0, 8.52MB)        dead after K23 (K6 writes o [0,8.39MB) later)
    //   B    = t3 then t5   bytes [8.52, 17.04MB)    dead after K5  (K7 writes up [8.39,41.94MB) later)
    //   R    = rsum         bytes [17.04, 25.43MB)   dead after K23 (K7 overwrites later)
    //   C (d_ws) = s then u (in-place), 8.52MB of 16MB ws
    _Float16* A  = (_Float16*)out;
    _Float16* Bb = (_Float16*)out + PBUF;
    _Float16* R  = (_Float16*)out + 2 * PBUF;
    _Float16* C  = (_Float16*)d_ws;
    (void)ws_size; (void)out_size; (void)n_in; (void)in_sizes;

    dim3 blk(256);

    // K1: t1 -> A, t3 -> B (pre-relu'd), rsum -> R
    attn_in_kernel<<<2048, blk, 0, stream>>>(in1, in2, A, Bb, R,
        wq, bq, wk, bk, wv, bv, rh, rw);
    // K23: s = attn1(t1) + attn3(t3) + rsum -> C
    attn_fused23_kernel<<<2048, blk, 0, stream>>>(A, Bb, R, C,
        wq, bq, wk, bk, wv, bv, rh, rw);
    // K4: t5 = relu(attn4(relu(s))) -> B
    attn4_kernel<<<2048, blk, 0, stream>>>(C, Bb,
        wq, bq, wk, bk, wv, bv, rh, rw);
    // K5: u = attn5(t5) + s -> C (in-place)
    attn5_kernel<<<2048, blk, 0, stream>>>(Bb, C,
        wq, bq, wk, bk, wv, bv, rh, rw);
    // K6: o = sigmoid(conv3x3(reflect_pad(u))) -> out[0:2M]
    conv_sig4_kernel<<<2048, blk, 0, stream>>>(C, cw, cb, out);
    // K7: up = bilinear2x(o) -> out[2M:]
    upsample4_kernel<<<8192, blk, 0, stream>>>(out, out + NPIX);
}

// Round 12
// 99.927 us; speedup vs baseline: 1.0373x; 1.0373x over previous
//
#include <hip/hip_runtime.h>

#if __has_builtin(__builtin_amdgcn_exp2f)
#define EXP2F(x) __builtin_amdgcn_exp2f(x)
#else
#define EXP2F(x) exp2f(x)
#endif

typedef float v2f __attribute__((ext_vector_type(2)));
typedef _Float16 h4v __attribute__((ext_vector_type(4)));   // 8B

constexpr int B = 8, H = 512, W = 512;
constexpr int PLANE = H * W;              // 262144
constexpr int BSTRIDE = 2 * PLANE;
constexpr int NPIX = B * PLANE;           // 2097152
constexpr int PPITCH = 520;               // padded row pitch (4 left, 4 right)
constexpr int PXOFF  = 4;
constexpr int PPLANE = H * PPITCH;        // 266240 halves per (b,ch) plane
constexpr int PBUF   = 16 * PPLANE;       // 4,259,840 halves per padded tensor (8.5MB)
constexpr float LOG2E = 1.4426950408889634f;

__device__ __forceinline__ float reluf(float v) { return v > 0.f ? v : 0.f; }
__device__ __forceinline__ float frcp(float v) { return __builtin_amdgcn_rcpf(v); }
__device__ __forceinline__ v2f vfma(v2f a, v2f b, v2f c) { return __builtin_elementwise_fma(a, b, c); }
__device__ __forceinline__ v2f vmax2(v2f a, v2f b) { return __builtin_elementwise_max(a, b); }
__device__ __forceinline__ v2f bc(float x) { v2f r; r.x = x; r.y = x; return r; }

// XCD-aware bijective work swizzle (8 XCDs, nwg % 8 == 0)
__device__ __forceinline__ unsigned swz8(unsigned bid, unsigned nwg)
{
    return (bid & 7u) * (nwg >> 3) + (bid >> 3);
}

struct AttnW {
    v2f wq0, wq1, bq;
    v2f wk0, wk1;
    v2f biasK[3];              // ((bk0+rh[r])*L, bk1*L)
    float rwL[3];              // rw[d]*L (ch1 additive)
    v2f wv0, wv1, bv;
};

__device__ __forceinline__ AttnW load_w(
    const float* wq, const float* bq, const float* wk, const float* bk,
    const float* wv, const float* bv, const float* rh, const float* rw, int i)
{
    AttnW P;
    P.wq0.x = wq[4*i];   P.wq0.y = wq[4*i+2];
    P.wq1.x = wq[4*i+1]; P.wq1.y = wq[4*i+3];
    P.bq.x  = bq[2*i];   P.bq.y  = bq[2*i+1];
    P.wk0.x = wk[4*i]   * LOG2E; P.wk0.y = wk[4*i+2] * LOG2E;
    P.wk1.x = wk[4*i+1] * LOG2E; P.wk1.y = wk[4*i+3] * LOG2E;
    float bk1L = bk[2*i+1] * LOG2E;
#pragma unroll
    for (int r = 0; r < 3; ++r) {
        P.biasK[r].x = (bk[2*i] + rh[3*i+r]) * LOG2E;
        P.biasK[r].y = bk1L;
    }
#pragma unroll
    for (int d = 0; d < 3; ++d) P.rwL[d] = rw[3*i+d] * LOG2E;
    P.wv0.x = wv[4*i];   P.wv0.y = wv[4*i+2];
    P.wv1.x = wv[4*i+1]; P.wv1.y = wv[4*i+3];
    P.bv.x  = bv[2*i];   P.bv.y  = bv[2*i+1];
    return P;
}

__device__ __forceinline__ void attn_strip(
    const v2f (&t)[3][6], const AttnW& P, v2f (&o)[4])
{
    v2f kk[3][6], vv[3][6];
#pragma unroll
    for (int r = 0; r < 3; ++r)
#pragma unroll
        for (int c = 0; c < 6; ++c) {
            v2f u0 = bc(t[r][c].x), u1 = bc(t[r][c].y);
            kk[r][c] = vfma(P.wk0, u0, vfma(P.wk1, u1, P.biasK[r]));
            vv[r][c] = vfma(P.wv0, u0, vfma(P.wv1, u1, P.bv));
        }
#pragma unroll
    for (int px = 0; px < 4; ++px) {
        v2f q = vfma(P.wq0, bc(t[1][px+1].x), vfma(P.wq1, bc(t[1][px+1].y), P.bq));
        v2f addv[3];
#pragma unroll
        for (int d = 0; d < 3; ++d) { addv[d].x = 0.f; addv[d].y = q.y * P.rwL[d]; }
        v2f s[9];
#pragma unroll
        for (int r = 0; r < 3; ++r)
#pragma unroll
            for (int d = 0; d < 3; ++d)
                s[r*3+d] = vfma(q, kk[r][px+d], addv[d]);
        v2f m = vmax2(vmax2(vmax2(vmax2(s[0], s[1]), vmax2(s[2], s[3])),
                            vmax2(vmax2(s[4], s[5]), vmax2(s[6], s[7]))), s[8]);
        v2f sum = bc(0.f), acc = bc(0.f);
#pragma unroll
        for (int r = 0; r < 3; ++r)
#pragma unroll
            for (int d = 0; d < 3; ++d) {
                v2f dd = s[r*3+d] - m;
                v2f e; e.x = EXP2F(dd.x); e.y = EXP2F(dd.y);
                sum += e;
                acc = vfma(e, vv[r][px+d], acc);
            }
        v2f rs; rs.x = frcp(sum.x); rs.y = frcp(sum.y);
        o[px] = acc * rs;
    }
}

// ---- fp16 padded-tensor helpers ----

// store 4-px strip (both channels), optional relu, + zero x-pads at row edges
template<bool RELU>
__device__ __forceinline__ void store_padded_h(
    _Float16* outp, int b2, int y, int x0, const v2f (&o)[4])
{
    int ob = b2 * PPLANE + y * PPITCH + x0 + PXOFF;   // multiple of 4 -> 8B aligned
    h4v h0, h1;
#pragma unroll
    for (int j = 0; j < 4; ++j) {
        float vx = RELU ? reluf(o[j].x) : o[j].x;
        float vy = RELU ? reluf(o[j].y) : o[j].y;
        h0[j] = (_Float16)vx;
        h1[j] = (_Float16)vy;
    }
    *reinterpret_cast<h4v*>(outp + ob)          = h0;
    *reinterpret_cast<h4v*>(outp + ob + PPLANE) = h1;
    if (x0 == 0 || x0 == W - 4) {
        h4v z; z.x = z.y = z.z = z.w = (_Float16)0.f;
        int pb = b2 * PPLANE + y * PPITCH + (x0 == 0 ? 0 : PXOFF + W);
        *reinterpret_cast<h4v*>(outp + pb)          = z;
        *reinterpret_cast<h4v*>(outp + pb + PPLANE) = z;
    }
}

// load 3x6 neighborhood from padded fp16 tensor (x-pads zero, y wave-uniform).
// 3 loads per row-ch: h4v centers + 2 scalar edges.
template<bool DO_RELU>
__device__ __forceinline__ void load_t_padded_h(
    unsigned s, const _Float16* __restrict__ xp, v2f (&t)[3][6])
{
    int x0 = (s & 127) * 4;
    int y  = (s >> 7) & 511;
    int b  = s >> 16;

    const _Float16* xb0 = xp + (b * 2) * PPLANE + x0 + PXOFF;
#pragma unroll
    for (int r = 0; r < 3; ++r) {
        int gy = y - 1 + r;
        bool ok = (unsigned)gy < (unsigned)H;   // wave-uniform
        int gyc = ok ? gy : y;
        const _Float16* p0 = xb0 + gyc * PPITCH;
        const _Float16* p1 = p0 + PPLANE;
        h4v m0 = *reinterpret_cast<const h4v*>(p0);
        h4v m1 = *reinterpret_cast<const h4v*>(p1);
        float l0 = (float)p0[-1], r0e = (float)p0[4];
        float l1 = (float)p1[-1], r1e = (float)p1[4];
        if (ok) {
            float u0[6] = { l0, (float)m0.x, (float)m0.y, (float)m0.z, (float)m0.w, r0e };
            float u1[6] = { l1, (float)m1.x, (float)m1.y, (float)m1.z, (float)m1.w, r1e };
#pragma unroll
            for (int c = 0; c < 6; ++c) {
                t[r][c].x = DO_RELU ? reluf(u0[c]) : u0[c];
                t[r][c].y = DO_RELU ? reluf(u1[c]) : u1[c];
            }
        } else {
#pragma unroll
            for (int c = 0; c < 6; ++c) { t[r][c].x = 0.f; t[r][c].y = 0.f; }
        }
    }
}

// load relu'd 3x6 neighborhood from UNPADDED f32 tensor (bounds-checked)
__device__ __forceinline__ void load_t_unpadded(
    unsigned s, const float* __restrict__ x, v2f (&t)[3][6])
{
    int x0 = (s & 127) * 4;
    int y  = (s >> 7) & 511;
    int b  = s >> 16;

    const float* xb = x + b * BSTRIDE;
    bool rowv[3] = { y > 0, true, y < H - 1 };
    int  yr[3]   = { y > 0 ? y - 1 : 0, y, y < H - 1 ? y + 1 : H - 1 };
    bool lv   = x0 > 0;
    bool rvld = x0 < W - 4;
    int  xl = lv ? x0 - 1 : 0;
    int  xr = rvld ? x0 + 4 : W - 1;

#pragma unroll
    for (int r = 0; r < 3; ++r) {
        const float* p0 = xb + yr[r] * W;
        const float* p1 = p0 + PLANE;
        float4 a0 = *reinterpret_cast<const float4*>(p0 + x0);
        float4 a1 = *reinterpret_cast<const float4*>(p1 + x0);
        float u0[6] = { p0[xl], a0.x, a0.y, a0.z, a0.w, p0[xr] };
        float u1[6] = { p1[xl], a1.x, a1.y, a1.z, a1.w, p1[xr] };
        bool rv_ = rowv[r];
#pragma unroll
        for (int c = 0; c < 6; ++c) {
            bool ok = rv_ && (c > 0 || lv) && (c < 5 || rvld);
            t[r][c].x = ok ? reluf(u0[c]) : 0.f;
            t[r][c].y = ok ? reluf(u1[c]) : 0.f;
        }
    }
}

// ---------------- kernels ----------------

// K1 (batched, grid 4096): t1 = relu(attn0(relu(in1))) -> A ;
//                          t3 = relu(attn2(relu(in2))) -> B   (fp16 padded, pre-relu'd)
__global__ __launch_bounds__(256) void attn_in_kernel(
    const float* __restrict__ xA, const float* __restrict__ xB,
    _Float16* outA, _Float16* outB,
    const float* __restrict__ wq, const float* __restrict__ bq,
    const float* __restrict__ wk, const float* __restrict__ bk,
    const float* __restrict__ wv, const float* __restrict__ bv,
    const float* __restrict__ rh, const float* __restrict__ rw,
    int piA, int piB)
{
    unsigned wid = swz8(blockIdx.x, 4096);
    bool second = wid >= 2048;
    AttnW P = load_w(wq, bq, wk, bk, wv, bv, rh, rw, second ? piB : piA);
    unsigned s = (second ? wid - 2048 : wid) * 256u + threadIdx.x;

    v2f t[3][6];
    load_t_unpadded(s, second ? xB : xA, t);
    v2f o[4];
    attn_strip(t, P, o);

    store_padded_h<true>(second ? outB : outA, (s >> 16) * 2, (s >> 7) & 511, (s & 127) * 4, o);
}

// K23 (fused): s = attn1(t1) + in1 + attn3(t3) + in2 -> C (fp16 padded, raw)
__global__ __launch_bounds__(256) void attn_fused23_kernel(
    const _Float16* __restrict__ A, const _Float16* __restrict__ Bb,
    const float* __restrict__ in1, const float* __restrict__ in2,
    _Float16* __restrict__ C,
    const float* __restrict__ wq, const float* __restrict__ bq,
    const float* __restrict__ wk, const float* __restrict__ bk,
    const float* __restrict__ wv, const float* __restrict__ bv,
    const float* __restrict__ rh, const float* __restrict__ rw)
{
    unsigned s = swz8(blockIdx.x, 2048) * 256u + threadIdx.x;
    int x0 = (s & 127) * 4;
    int y  = (s >> 7) & 511;
    int b  = s >> 16;
    int base0 = b * BSTRIDE + y * W + x0;
    int base1 = base0 + PLANE;

    v2f t[3][6];
    v2f o1[4], o2[4];

    {
        AttnW P1 = load_w(wq, bq, wk, bk, wv, bv, rh, rw, 1);
        load_t_padded_h<false>(s, A, t);    // t1 stored pre-relu'd
        attn_strip(t, P1, o1);
        float4 ra = *reinterpret_cast<const float4*>(in1 + base0);
        float4 rb = *reinterpret_cast<const float4*>(in1 + base1);
        o1[0].x += ra.x; o1[1].x += ra.y; o1[2].x += ra.z; o1[3].x += ra.w;
        o1[0].y += rb.x; o1[1].y += rb.y; o1[2].y += rb.z; o1[3].y += rb.w;
    }
    {
        AttnW P3 = load_w(wq, bq, wk, bk, wv, bv, rh, rw, 3);
        load_t_padded_h<false>(s, Bb, t);   // t3 stored pre-relu'd
        attn_strip(t, P3, o2);
        float4 ra = *reinterpret_cast<const float4*>(in2 + base0);
        float4 rb = *reinterpret_cast<const float4*>(in2 + base1);
        o2[0].x += ra.x + o1[0].x; o2[1].x += ra.y + o1[1].x;
        o2[2].x += ra.z + o1[2].x; o2[3].x += ra.w + o1[3].x;
        o2[0].y += rb.x + o1[0].y; o2[1].y += rb.y + o1[1].y;
        o2[2].y += rb.z + o1[2].y; o2[3].y += rb.w + o1[3].y;
    }

    store_padded_h<false>(C, b * 2, y, x0, o2);   // s raw (K5 residual needs it)
}

// K4: t5 = relu(attn4(relu(s))) -> B (fp16 padded)
__global__ __launch_bounds__(256) void attn4_kernel(
    const _Float16* __restrict__ C, _Float16* __restrict__ Bb,
    const float* __restrict__ wq, const float* __restrict__ bq,
    const float* __restrict__ wk, const float* __restrict__ bk,
    const float* __restrict__ wv, const float* __restrict__ bv,
    const float* __restrict__ rh, const float* __restrict__ rw)
{
    unsigned s = swz8(blockIdx.x, 2048) * 256u + threadIdx.x;
    AttnW P = load_w(wq, bq, wk, bk, wv, bv, rh, rw, 4);
    v2f t[3][6];
    load_t_padded_h<true>(s, C, t);        // s raw -> relu on load
    v2f o[4];
    attn_strip(t, P, o);
    store_padded_h<true>(Bb, (s >> 16) * 2, (s >> 7) & 511, (s & 127) * 4, o);
}

// K5: u = attn5(t5) + s -> C in-place (own-pixel read+write; pads untouched)
__global__ __launch_bounds__(256) void attn5_kernel(
    const _Float16* __restrict__ Bb, _Float16* __restrict__ C,
    const float* __restrict__ wq, const float* __restrict__ bq,
    const float* __restrict__ wk, const float* __restrict__ bk,
    const float* __restrict__ wv, const float* __restrict__ bv,
    const float* __restrict__ rh, const float* __restrict__ rw)
{
    unsigned s = swz8(blockIdx.x, 2048) * 256u + threadIdx.x;
    AttnW P = load_w(wq, bq, wk, bk, wv, bv, rh, rw, 5);
    v2f t[3][6];
    load_t_padded_h<false>(s, Bb, t);      // t5 stored pre-relu'd
    v2f o[4];
    attn_strip(t, P, o);

    int x0 = (s & 127) * 4;
    int y  = (s >> 7) & 511;
    int b  = s >> 16;
    int ob = (b * 2) * PPLANE + y * PPITCH + x0 + PXOFF;
    h4v r0 = *reinterpret_cast<const h4v*>(C + ob);
    h4v r1 = *reinterpret_cast<const h4v*>(C + ob + PPLANE);
    h4v h0, h1;
#pragma unroll
    for (int j = 0; j < 4; ++j) {
        h0[j] = (_Float16)(o[j].x + (float)r0[j]);
        h1[j] = (_Float16)(o[j].y + (float)r1[j]);
    }
    *reinterpret_cast<h4v*>(C + ob)          = h0;
    *reinterpret_cast<h4v*>(C + ob + PPLANE) = h1;
}

// K6: o = sigmoid(conv3x3(reflect_pad(u))) ; u fp16 padded -> f32 out[0:2M]
__global__ __launch_bounds__(256) void conv_sig4_kernel(
    const _Float16* __restrict__ u,
    const float* __restrict__ cw, const float* __restrict__ cb,
    float* __restrict__ o)
{
    unsigned s = swz8(blockIdx.x, 2048) * 256u + threadIdx.x;
    int x0 = (s & 127) * 4;
    int y  = (s >> 7) & 511;
    int b  = s >> 16;

    float w[18];
#pragma unroll
    for (int i = 0; i < 18; ++i) w[i] = cw[i];

    int yy[3];
#pragma unroll
    for (int i = 0; i < 3; ++i) {
        int t = y + i - 1;
        if (t < 0) t = -t;
        if (t > H - 1) t = 2 * (H - 1) - t;
        yy[i] = t;
    }
    int xl = x0 - 1; if (xl < 0) xl = 1;
    int xr = x0 + 4; if (xr > W - 1) xr = 2 * (W - 1) - xr;

    float acc[4] = { cb[0], cb[0], cb[0], cb[0] };
#pragma unroll
    for (int c = 0; c < 2; ++c) {
        const _Float16* up = u + (b * 2 + c) * PPLANE + PXOFF;
#pragma unroll
        for (int i = 0; i < 3; ++i) {
            const _Float16* row = up + yy[i] * PPITCH;
            h4v m0 = *reinterpret_cast<const h4v*>(row + x0);
            float t6[6] = { (float)row[xl], (float)m0.x, (float)m0.y,
                            (float)m0.z, (float)m0.w, (float)row[xr] };
#pragma unroll
            for (int j = 0; j < 3; ++j) {
                float wc = w[c * 9 + i * 3 + j];
#pragma unroll
                for (int px = 0; px < 4; ++px)
                    acc[px] = fmaf(t6[px + j], wc, acc[px]);
            }
        }
    }
    float4 ov;
    ov.x = frcp(1.f + EXP2F(-acc[0] * LOG2E));
    ov.y = frcp(1.f + EXP2F(-acc[1] * LOG2E));
    ov.z = frcp(1.f + EXP2F(-acc[2] * LOG2E));
    ov.w = frcp(1.f + EXP2F(-acc[3] * LOG2E));
    *reinterpret_cast<float4*>(o + b * PLANE + y * W + x0) = ov;
}

// K7: 2x bilinear upsample (linspace(0,511,1024) grid); o is f32
__global__ __launch_bounds__(256) void upsample4_kernel(
    const float* __restrict__ o, float* __restrict__ up)
{
    unsigned p = swz8(blockIdx.x, 8192) * 256u + threadIdx.x;
    int b  = p >> 18;
    int y  = (p >> 8) & 1023;
    int x0 = (p & 255) * 4;

    const float scale = 511.0f / 1023.0f;
    float fy = y * scale;
    int y0 = (int)fy;
    float wy = fy - y0;
    int y1 = min(y0 + 1, H - 1);

    const float* ob = o + b * PLANE;
    const float* row0 = ob + y0 * W;
    const float* row1 = ob + y1 * W;

    float4 ov;
    float* ovp = &ov.x;
#pragma unroll
    for (int j = 0; j < 4; ++j) {
        float fx = (x0 + j) * scale;
        int xi = (int)fx;
        float wx = fx - xi;
        int xi1 = min(xi + 1, W - 1);
        float v00 = row0[xi], v01 = row0[xi1];
        float v10 = row1[xi], v11 = row1[xi1];
        float top = fmaf(v01 - v00, wx, v00);
        float bot = fmaf(v11 - v10, wx, v10);
        ovp[j] = fmaf(bot - top, wy, top);
    }
    *reinterpret_cast<float4*>(up + ((long)b << 20) + y * 1024 + x0) = ov;
}

extern "C" void kernel_launch(void* const* d_in, const int* in_sizes, int n_in,
                              void* d_out, int out_size, void* d_ws, size_t ws_size,
                              hipStream_t stream) {
    const float* in1 = (const float*)d_in[0];
    const float* in2 = (const float*)d_in[1];
    const float* wq  = (const float*)d_in[2];
    const float* bq  = (const float*)d_in[3];
    const float* wk  = (const float*)d_in[4];
    const float* bk  = (const float*)d_in[5];
    const float* wv  = (const float*)d_in[6];
    const float* bv  = (const float*)d_in[7];
    const float* rh  = (const float*)d_in[8];
    const float* rw  = (const float*)d_in[9];
    const float* cw  = (const float*)d_in[10];
    const float* cb  = (const float*)d_in[11];

    float* out = (float*)d_out;
    // fp16 padded tensors (8.5MB each):
    //   A = t1            in d_out bytes [0, 8.52MB)   dead after K23 (K6 writes o [0,8.39MB) later)
    //   B = t3 then t5    in d_out bytes [8.52,17.04MB) dead after K5 (K7 writes up [8.39,41.94MB) later)
    //   C = s then u      in d_ws (8.52MB of 16MB)
    _Float16* A  = (_Float16*)out;
    _Float16* Bb = (_Float16*)out + PBUF;
    _Float16* C  = (_Float16*)d_ws;
    (void)ws_size; (void)out_size; (void)n_in; (void)in_sizes;

    dim3 blk(256);

    // K1: t1 -> A, t3 -> B (pre-relu'd)
    attn_in_kernel<<<4096, blk, 0, stream>>>(in1, in2, A, Bb,
        wq, bq, wk, bk, wv, bv, rh, rw, 0, 2);
    // K23: s = attn1(t1) + in1 + attn3(t3) + in2 -> C
    attn_fused23_kernel<<<2048, blk, 0, stream>>>(A, Bb, in1, in2, C,
        wq, bq, wk, bk, wv, bv, rh, rw);
    // K4: t5 = relu(attn4(relu(s))) -> B
    attn4_kernel<<<2048, blk, 0, stream>>>(C, Bb,
        wq, bq, wk, bk, wv, bv, rh, rw);
    // K5: u = attn5(t5) + s -> C (in-place)
    attn5_kernel<<<2048, blk, 0, stream>>>(Bb, C,
        wq, bq, wk, bk, wv, bv, rh, rw);
    // K6: o = sigmoid(conv3x3(reflect_pad(u))) -> out[0:2M]
    conv_sig4_kernel<<<2048, blk, 0, stream>>>(C, cw, cb, out);
    // K7: up = bilinear2x(o) -> out[2M:]
    upsample4_kernel<<<8192, blk, 0, stream>>>(out, out + NPIX);
}